// Round 6
// baseline (519.665 us; speedup 1.0000x reference)
//
#include <hip/hip_runtime.h>

#define SB 16
#define SN 2048
#define SD 128
#define NM 2049
#define SZ (SB*SN*SD)     // elements per (B,N,D) tensor
#define WLDS 17408        // padded weight matrix in LDS: 128 rows * 136

typedef __bf16 bf16x8 __attribute__((ext_vector_type(8)));
typedef float f32x4 __attribute__((ext_vector_type(4)));

// float -> bf16 round-to-nearest-even
__device__ __forceinline__ unsigned short f2b(float f){
  union { float f; unsigned int u; } v; v.f = f;
  unsigned int r = v.u + 0x7fffu + ((v.u >> 16) & 1u);
  return (unsigned short)(r >> 16);
}
// float -> bf16 round-half-up (2 VALU; P in [0,1], no NaN/overflow)
__device__ __forceinline__ unsigned short f2b_fast(float f){
  union { float f; unsigned int u; } v; v.f = f;
  return (unsigned short)((v.u + 0x8000u) >> 16);
}

__device__ __forceinline__ void async16(const void* g, void* l){
  __builtin_amdgcn_global_load_lds(
      (__attribute__((address_space(1))) void*)(g),
      (__attribute__((address_space(3))) void*)(l), 16, 0, 0);
}

// ---- blocks [0,64): transpose+cvt 4 weight matrices -> wts (bf16, [n][k])
// ---- blocks [64,1088): pack mask[b,1+i,1+j] -> pm bits [b][i][kt] (uint64, bit=key)
__global__ __launch_bounds__(256) void prep_pack_kernel(
    const float* __restrict__ Wq, const float* __restrict__ Wk,
    const float* __restrict__ Wv, const float* __restrict__ Wo,
    const int* __restrict__ mask,
    unsigned short* __restrict__ wts, unsigned long long* __restrict__ pm)
{
  if (blockIdx.x < 64){
    int widx = blockIdx.x >> 4;
    int kg   = blockIdx.x & 15;
    const float* W = (widx==0)?Wq:(widx==1)?Wk:(widx==2)?Wv:Wo;
    unsigned short* O = wts + widx*16384;
    int t = threadIdx.x;
    int k = kg*8 + (t>>5);
    int n = (t&31)*4;
    float4 v = *reinterpret_cast<const float4*>(W + k*SD + n);
    O[(n+0)*SD + k] = f2b(v.x);
    O[(n+1)*SD + k] = f2b(v.y);
    O[(n+2)*SD + k] = f2b(v.z);
    O[(n+3)*SD + k] = f2b(v.w);
    return;
  }
  int widx = blockIdx.x - 64;                 // 0..1023
  int wave = widx*4 + (threadIdx.x>>6);       // 0..4095
  int ln = threadIdx.x & 63;
  size_t wb0 = (size_t)wave*256;              // 256 words per wave, 1048576 total
  for (int rr=0; rr<32; rr++){
    size_t wb = wb0 + rr*8;
    int v[8];
    for (int i=0;i<8;i++){
      size_t wbi = wb + i;
      int bb = (int)(wbi>>16); int rem = (int)(wbi & 65535);
      int row = rem>>5; int kt = rem&31;
      v[i] = mask[(size_t)bb*NM*NM + (size_t)(row+1)*NM + 1 + kt*64 + ln];
    }
    unsigned long long bt[8];
    for (int i=0;i<8;i++) bt[i] = __ballot(v[i]!=0);
    if (ln==0){
      for (int i=0;i<4;i++){
        ulonglong2 t; t.x = bt[2*i]; t.y = bt[2*i+1];
        *reinterpret_cast<ulonglong2*>(&pm[wb + 2*i]) = t;
      }
    }
  }
}

// ---- fused q/k/v projections, weights staged in padded LDS (no global deps in d-loop)
// blocks [0,512): 64 query rows -> qb (pre-scaled 1/sqrt(D))
// blocks [512,1024): 64 key rows -> kb, then v=k@Wv+bv -> vt [b][d][n]
__global__ __launch_bounds__(256) void qkv_kernel(
    const float* __restrict__ query, const float* __restrict__ key,
    const unsigned short* __restrict__ wts,
    const float* __restrict__ bq, const float* __restrict__ bk,
    const float* __restrict__ bv,
    unsigned short* __restrict__ qb, unsigned short* __restrict__ kb,
    unsigned short* __restrict__ vt)
{
  __shared__ unsigned short lds[2*WLDS + 9216];   // 86 KB
  int tid=threadIdx.x;
  int w=tid>>6, ln=tid&63, g=ln>>4, lm=ln&15;
  bool isq = blockIdx.x < 512;
  int id = isq ? blockIdx.x : (blockIdx.x - 512);
  int bb = id>>5, n0 = (id&31)*64;
  size_t rowbase = (size_t)bb*SN + n0 + w*16;
  const float sc = 0.08838834764831845f;  // 1/sqrt(128)

  if (isq){
    for (int i=0;i<8;i++){                 // stage Wq, padded stride 136
      int p = i*256+tid; int row=p>>4, c=p&15;
      uint4 t = *reinterpret_cast<const uint4*>(wts + p*8);
      *reinterpret_cast<uint4*>(&lds[row*136 + c*8]) = t;
    }
    __syncthreads();
    float bqv[8];
    for (int d=0;d<8;d++) bqv[d] = bq[d*16+lm];
    const float* xr = query + (rowbase + lm)*SD;
    bf16x8 af[4];
    for (int ks=0;ks<4;ks++){
      float4 x0 = *reinterpret_cast<const float4*>(xr + ks*32 + g*8);
      float4 x1 = *reinterpret_cast<const float4*>(xr + ks*32 + g*8 + 4);
      union { bf16x8 v; unsigned short s[8]; } u;
      u.s[0]=f2b(x0.x); u.s[1]=f2b(x0.y); u.s[2]=f2b(x0.z); u.s[3]=f2b(x0.w);
      u.s[4]=f2b(x1.x); u.s[5]=f2b(x1.y); u.s[6]=f2b(x1.z); u.s[7]=f2b(x1.w);
      af[ks]=u.v;
    }
    for (int d=0; d<8; d++){
      f32x4 acc = {0.f,0.f,0.f,0.f};
      for (int ks=0;ks<4;ks++){
        bf16x8 wf = *reinterpret_cast<const bf16x8*>(&lds[(d*16+lm)*136 + ks*32 + g*8]);
        acc = __builtin_amdgcn_mfma_f32_16x16x32_bf16(af[ks], wf, acc, 0,0,0);
      }
      for (int r=0;r<4;r++)
        qb[(rowbase + 4*g + r)*SD + d*16 + lm] = f2b((acc[r]+bqv[d])*sc);
    }
  } else {
    for (int i=0;i<8;i++){                 // stage Wk
      int p = i*256+tid; int row=p>>4, c=p&15;
      uint4 t = *reinterpret_cast<const uint4*>(wts + 16384 + p*8);
      *reinterpret_cast<uint4*>(&lds[row*136 + c*8]) = t;
    }
    for (int i=0;i<8;i++){                 // stage Wv
      int p = i*256+tid; int row=p>>4, c=p&15;
      uint4 t = *reinterpret_cast<const uint4*>(wts + 32768 + p*8);
      *reinterpret_cast<uint4*>(&lds[WLDS + row*136 + c*8]) = t;
    }
    __syncthreads();
    float bkv[8], bvv[8];
    for (int d=0;d<8;d++){ bkv[d]=bk[d*16+lm]; bvv[d]=bv[d*16+lm]; }
    const float* xr = key + (rowbase + lm)*SD;
    bf16x8 af[4];
    for (int ks=0;ks<4;ks++){
      float4 x0 = *reinterpret_cast<const float4*>(xr + ks*32 + g*8);
      float4 x1 = *reinterpret_cast<const float4*>(xr + ks*32 + g*8 + 4);
      union { bf16x8 v; unsigned short s[8]; } u;
      u.s[0]=f2b(x0.x); u.s[1]=f2b(x0.y); u.s[2]=f2b(x0.z); u.s[3]=f2b(x0.w);
      u.s[4]=f2b(x1.x); u.s[5]=f2b(x1.y); u.s[6]=f2b(x1.z); u.s[7]=f2b(x1.w);
      af[ks]=u.v;
    }
    unsigned short* strip = &lds[2*WLDS + w*2176];   // 16 rows x 136
    for (int d=0; d<8; d++){
      f32x4 acc = {0.f,0.f,0.f,0.f};
      for (int ks=0;ks<4;ks++){
        bf16x8 wf = *reinterpret_cast<const bf16x8*>(&lds[(d*16+lm)*136 + ks*32 + g*8]);
        acc = __builtin_amdgcn_mfma_f32_16x16x32_bf16(af[ks], wf, acc, 0,0,0);
      }
      for (int r=0;r<4;r++){
        unsigned short kv2 = f2b(acc[r]+bkv[d]);
        kb[(rowbase + 4*g + r)*SD + d*16 + lm] = kv2;
        strip[(4*g+r)*136 + d*16 + lm] = kv2;
      }
    }
    bf16x8 ka[4];                          // k as A-frags (per-wave strip)
    for (int ks=0;ks<4;ks++)
      ka[ks] = *reinterpret_cast<const bf16x8*>(&strip[lm*136 + ks*32 + g*8]);
    __syncthreads();                       // all ka read; scratch reusable as vT
    unsigned short* vT = &lds[2*WLDS];     // [d 128][n-local 64], stride 72
    for (int d=0; d<8; d++){
      f32x4 acc = {0.f,0.f,0.f,0.f};
      for (int ks=0;ks<4;ks++){
        bf16x8 wf = *reinterpret_cast<const bf16x8*>(&lds[WLDS + (d*16+lm)*136 + ks*32 + g*8]);
        acc = __builtin_amdgcn_mfma_f32_16x16x32_bf16(ka[ks], wf, acc, 0,0,0);
      }
      ushort4 pk;
      pk.x=f2b(acc[0]+bvv[d]); pk.y=f2b(acc[1]+bvv[d]);
      pk.z=f2b(acc[2]+bvv[d]); pk.w=f2b(acc[3]+bvv[d]);
      *reinterpret_cast<ushort4*>(&vT[(d*16+lm)*72 + w*16 + 4*g]) = pk;
    }
    __syncthreads();
    for (int i=0;i<4;i++){                 // vt[b][d][n0..n0+63], coalesced
      int idx = i*256+tid; int row = idx>>3, c8 = idx&7;
      uint4 t = *reinterpret_cast<const uint4*>(&vT[row*72 + c8*8]);
      *reinterpret_cast<uint4*>(vt + (size_t)bb*SD*SN + (size_t)row*SN + n0 + c8*8) = t;
    }
  }
}

// ---- flash attention + fused output projection; mask from packed bits ----
__global__ __launch_bounds__(256,4) void flash_kernel(
    const unsigned short* __restrict__ qb, const unsigned short* __restrict__ kb,
    const unsigned short* __restrict__ vt, const unsigned long long* __restrict__ pm,
    const unsigned short* __restrict__ WoT, const float* __restrict__ bo,
    float* __restrict__ out)
{
  __shared__ unsigned short bufK[2][64*128];   // [key][d], chunk-swizzled
  __shared__ unsigned short bufV[2][128*64];   // [d][key], chunk-swizzled
  __shared__ unsigned short ldsP[4*16*72];     // per-wave P strip

  int tid=threadIdx.x;
  int w=tid>>6, ln=tid&63, g=ln>>4, lm=ln&15;
  int b = blockIdx.x >> 5, qt = blockIdx.x & 31;
  int q0 = qt*64;

  const unsigned short* Qb = qb + (size_t)b*SN*SD;
  const unsigned short* Kb = kb + (size_t)b*SN*SD;
  const unsigned short* Vb = vt + (size_t)b*SD*SN;

  auto issueK = [&](int k0, int bi){
    const char* gbase = (const char*)Kb + (size_t)k0*256;
    for (int c=0;c<4;c++){
      int p = c*256 + tid;
      int row = p>>4, lc = (p&15) ^ (row&15);
      async16(gbase + (size_t)row*256 + lc*16, (char*)bufK[bi] + p*16);
    }
  };
  auto issueV = [&](int k0, int bi){
    const char* gbase = (const char*)Vb + (size_t)k0*2;
    for (int c=0;c<4;c++){
      int p = c*256 + tid;
      int row = p>>3, lc = (p&7) ^ (row&7);
      async16(gbase + (size_t)row*4096 + lc*16, (char*)bufV[bi] + p*16);
    }
  };

  issueK(0,0); issueV(0,0);

  bf16x8 qf[4];
  {
    const unsigned short* qr = Qb + (size_t)(q0 + w*16 + lm)*SD;
    for (int ks=0;ks<4;ks++)
      qf[ks] = *reinterpret_cast<const bf16x8*>(qr + ks*32 + g*8);
  }

  // packed-mask row pointers: rows q0+w*16+4g+r, 32 words/row
  const unsigned long long* pmr = pm + ((size_t)b*SN + q0 + w*16 + 4*g)*32;
  unsigned long long pmc[4];
  for (int r=0;r<4;r++) pmc[r] = pmr[(size_t)r*32];

  float mrow[4], lrow[4], al[4];
  f32x4 acc[8];
  for (int r=0;r<4;r++){ mrow[r]=-INFINITY; lrow[r]=0.f; }
  for (int d=0;d<8;d++){ f32x4 z={0.f,0.f,0.f,0.f}; acc[d]=z; }
  unsigned short* pw = &ldsP[w*16*72];

  for (int kt=0; kt<32; kt++){
    __syncthreads();          // DMA for buf[kt&1] drained; reads of buf[kt&1^1] done
    int cur = kt&1;
    if (kt<31){ issueK((kt+1)*64, cur^1); issueV((kt+1)*64, cur^1); }

    // S = Q K^T (wave strip: 16 q-rows x 64 keys), swizzled reads
    f32x4 s[4];
    for (int ct=0;ct<4;ct++){
      f32x4 z = {0.f,0.f,0.f,0.f};
      for (int ks=0;ks<4;ks++){
        bf16x8 kf = *reinterpret_cast<const bf16x8*>(
            &bufK[cur][(ct*16+lm)*128 + (((ks*4+g)^lm))*8]);
        z = __builtin_amdgcn_mfma_f32_16x16x32_bf16(qf[ks], kf, z, 0,0,0);
      }
      s[ct]=z;
    }

    // inverted mask from bits (true -> -inf), then prefetch next tile's words
    for (int r=0;r<4;r++){
      unsigned int lo = (unsigned int)pmc[r];
      unsigned int hi = (unsigned int)(pmc[r]>>32);
      unsigned int l = lo >> lm, h = hi >> lm;
      if (l & 1u)       s[0][r] = -INFINITY;
      if (l & 0x10000u) s[1][r] = -INFINITY;
      if (h & 1u)       s[2][r] = -INFINITY;
      if (h & 0x10000u) s[3][r] = -INFINITY;
    }
    if (kt<31)
      for (int r=0;r<4;r++) pmc[r] = pmr[(size_t)r*32 + kt + 1];

    // online softmax
    for (int r=0;r<4;r++){
      float v = fmaxf(fmaxf(s[0][r],s[1][r]), fmaxf(s[2][r],s[3][r]));
      v = fmaxf(v, __shfl_xor(v,1,16));
      v = fmaxf(v, __shfl_xor(v,2,16));
      v = fmaxf(v, __shfl_xor(v,4,16));
      v = fmaxf(v, __shfl_xor(v,8,16));
      float mn = fmaxf(mrow[r], v);
      bool dead = (mn == -INFINITY);    // fully-masked so far -> zeros (NaN->0)
      float a = dead ? 1.f : __expf(mrow[r]-mn);
      float rsum = 0.f;
      for (int ct=0;ct<4;ct++){
        float p = dead ? 0.f : __expf(s[ct][r]-mn);
        s[ct][r]=p; rsum += p;
      }
      rsum += __shfl_xor(rsum,1,16);
      rsum += __shfl_xor(rsum,2,16);
      rsum += __shfl_xor(rsum,4,16);
      rsum += __shfl_xor(rsum,8,16);
      lrow[r] = lrow[r]*a + rsum;
      mrow[r] = mn;
      al[r] = a;
    }
    for (int d=0;d<8;d++)
      for (int r=0;r<4;r++)
        acc[d][r] *= al[r];

    // P: C-layout -> per-wave LDS strip -> A-frags
    for (int ct=0;ct<4;ct++){
      int col = ct*16+lm;
      for (int r=0;r<4;r++)
        pw[(4*g+r)*72 + col] = f2b_fast(s[ct][r]);
    }
    bf16x8 pa0 = *reinterpret_cast<const bf16x8*>(&pw[lm*72 + g*8]);
    bf16x8 pa1 = *reinterpret_cast<const bf16x8*>(&pw[lm*72 + 32 + g*8]);

    // O += P V (swizzled V reads)
    for (int d=0;d<8;d++){
      bf16x8 v0 = *reinterpret_cast<const bf16x8*>(
          &bufV[cur][(d*16+lm)*64 + ((g^(lm&7)))*8]);
      acc[d] = __builtin_amdgcn_mfma_f32_16x16x32_bf16(pa0, v0, acc[d], 0,0,0);
      bf16x8 v1 = *reinterpret_cast<const bf16x8*>(
          &bufV[cur][(d*16+lm)*64 + (((4+g)^(lm&7)))*8]);
      acc[d] = __builtin_amdgcn_mfma_f32_16x16x32_bf16(pa1, v1, acc[d], 0,0,0);
    }
  }

  // epilogue: out = (O/l) @ Wo + bo
  __syncthreads();            // done with bufK/bufV; reuse as bf16 A-frag strips
  float inv[4];
  for (int r=0;r<4;r++) inv[r] = (lrow[r] > 0.f) ? (1.f/lrow[r]) : 0.f;
  unsigned short* strip = &bufK[0][0] + w*2176;   // 16 rows x 136 stride
  for (int d=0;d<8;d++)
    for (int r=0;r<4;r++)
      strip[(4*g+r)*136 + d*16 + lm] = f2b(acc[d][r]*inv[r]);
  bf16x8 oa[4];
  for (int ks=0;ks<4;ks++)
    oa[ks] = *reinterpret_cast<const bf16x8*>(&strip[lm*136 + ks*32 + g*8]);
  float* Ob = out + ((size_t)b*SN + q0 + w*16)*SD;
  for (int dc=0; dc<8; dc++){
    f32x4 o = {0.f,0.f,0.f,0.f};
    for (int ks=0;ks<4;ks++){
      bf16x8 wf = *reinterpret_cast<const bf16x8*>(WoT + (dc*16+lm)*SD + ks*32 + g*8);
      o = __builtin_amdgcn_mfma_f32_16x16x32_bf16(oa[ks], wf, o, 0,0,0);
    }
    float bb = bo[dc*16+lm];
    for (int r=0;r<4;r++)
      Ob[(size_t)(4*g+r)*SD + dc*16 + lm] = o[r]+bb;
  }
}

extern "C" void kernel_launch(void* const* d_in, const int* in_sizes, int n_in,
                              void* d_out, int out_size, void* d_ws, size_t ws_size,
                              hipStream_t stream)
{
  const float* query = (const float*)d_in[0];
  const float* key   = (const float*)d_in[1];
  const int*   mask  = (const int*)d_in[2];
  const float* Wq = (const float*)d_in[3];
  const float* bq = (const float*)d_in[4];
  const float* Wk = (const float*)d_in[5];
  const float* bk = (const float*)d_in[6];
  const float* Wv = (const float*)d_in[7];
  const float* bv = (const float*)d_in[8];
  const float* Wo = (const float*)d_in[9];
  const float* bo = (const float*)d_in[10];
  float* out = (float*)d_out;

  // workspace: qb, kb, vt (bf16, 8MB each) + wts (128KB) + pm (8MB) = ~33.7MB
  unsigned short* qb = (unsigned short*)d_ws;
  unsigned short* kb = qb + SZ;
  unsigned short* vt = kb + SZ;
  unsigned short* wts = vt + SZ;                         // 4 x 16384 ushorts
  unsigned long long* pm = (unsigned long long*)(wts + 65536);

  prep_pack_kernel<<<1088,256,0,stream>>>(Wq,Wk,Wv,Wo, mask, wts, pm);
  qkv_kernel      <<<1024,256,0,stream>>>(query, key, wts, bq, bk, bv, qb, kb, vt);
  flash_kernel    <<<512,256,0,stream>>>(qb, kb, vt, pm, wts+49152, bo, out);
}